// Round 4
// baseline (781.481 us; speedup 1.0000x reference)
//
#include <hip/hip_runtime.h>

#define N_NODES 100000
#define N_EDGES 1600000

typedef __attribute__((ext_vector_type(8))) _Float16 half8;
typedef __attribute__((ext_vector_type(4))) _Float16 half4v;
typedef __attribute__((ext_vector_type(4))) float floatx4;

// ---------------- CSR build ----------------
// Pass 1: degree count + per-edge rank (removes atomics from the fill pass).

__global__ void deg_rank(const int* __restrict__ dst, int* __restrict__ deg,
                         int* __restrict__ rank, int e) {
    int i = blockIdx.x * blockDim.x + threadIdx.x;
    if (i < e) rank[i] = atomicAdd(&deg[dst[i]], 1);
}

// Multi-block exclusive scan of deg -> offs. Chunk = 2048/block. NB = 49.

__global__ __launch_bounds__(256) void scan_partial(const int* __restrict__ deg,
                                                    int* __restrict__ bsum, int n) {
    __shared__ int wsum[4];
    int t = threadIdx.x;
    int base = blockIdx.x * 2048 + t * 8;
    int tsum = 0;
    #pragma unroll
    for (int k = 0; k < 8; ++k) {
        int idx = base + k;
        tsum += (idx < n) ? deg[idx] : 0;
    }
    #pragma unroll
    for (int d = 1; d < 64; d <<= 1) tsum += __shfl_xor(tsum, d, 64);
    if ((t & 63) == 0) wsum[t >> 6] = tsum;
    __syncthreads();
    if (t == 0) bsum[blockIdx.x] = wsum[0] + wsum[1] + wsum[2] + wsum[3];
}

__global__ void scan_blocksums(const int* __restrict__ bsum, int* __restrict__ bbase, int nb) {
    int t = threadIdx.x;               // 64 threads
    int v = (t < nb) ? bsum[t] : 0;
    int s = v;
    #pragma unroll
    for (int d = 1; d < 64; d <<= 1) {
        int u = __shfl_up(s, d, 64);
        if (t >= d) s += u;
    }
    if (t < nb) bbase[t] = s - v;
    if (t == 63) bbase[nb] = s;
}

__global__ __launch_bounds__(256) void scan_write(const int* __restrict__ deg,
                                                  const int* __restrict__ bbase,
                                                  int* __restrict__ offs, int n, int nb) {
    __shared__ int wsum[4];
    int t = threadIdx.x;
    int lane = t & 63, w = t >> 6;
    int base = blockIdx.x * 2048 + t * 8;
    int v[8];
    #pragma unroll
    for (int k = 0; k < 8; ++k) {
        int idx = base + k;
        v[k] = (idx < n) ? deg[idx] : 0;
    }
    int tsum = 0;
    #pragma unroll
    for (int k = 0; k < 8; ++k) { int x = v[k]; v[k] = tsum; tsum += x; }
    int s = tsum;
    #pragma unroll
    for (int d = 1; d < 64; d <<= 1) {
        int u = __shfl_up(s, d, 64);
        if (lane >= d) s += u;
    }
    if (lane == 63) wsum[w] = s;
    __syncthreads();
    int wb = 0;
    for (int j = 0; j < w; ++j) wb += wsum[j];
    int texcl = bbase[blockIdx.x] + wb + (s - tsum);
    #pragma unroll
    for (int k = 0; k < 8; ++k) {
        int idx = base + k;
        if (idx < n) offs[idx] = texcl + v[k];
    }
    if (blockIdx.x == 0 && t == 0) offs[n] = bbase[nb];
}

// Pass 2: atomic-free CSR fill using precomputed ranks.
__global__ void fill_csr2(const int* __restrict__ src, const int* __restrict__ dst,
                          const int* __restrict__ offs, const int* __restrict__ rank,
                          int* __restrict__ csr, int e) {
    int i = blockIdx.x * blockDim.x + threadIdx.x;
    if (i < e) csr[offs[dst[i]] + rank[i]] = src[i];
}

// ---------------- x -> fp16 convert ----------------

__global__ void cvt_f16(const float4* __restrict__ in, half4v* __restrict__ oh, int n4) {
    int i = blockIdx.x * blockDim.x + threadIdx.x;
    if (i >= n4) return;
    float4 v = in[i];
    half4v h;
    h[0] = (_Float16)v.x; h[1] = (_Float16)v.y;
    h[2] = (_Float16)v.z; h[3] = (_Float16)v.w;
    oh[i] = h;
}

// ---------------- fused weight prep (all 6 weights, one launch) ----------------
// W[K][dout] fp32 -> Wt[npad][K] fp16.
// NOTE: 12288 is NOT a power of two -- use subtraction, never masking (r8 bug).

__global__ void prep_all(const float* __restrict__ ws1, const float* __restrict__ wn1,
                         const float* __restrict__ ws2, const float* __restrict__ wn2,
                         const float* __restrict__ ws3, const float* __restrict__ wn3,
                         _Float16* __restrict__ o1s, _Float16* __restrict__ o1n,
                         _Float16* __restrict__ o2s, _Float16* __restrict__ o2n,
                         _Float16* __restrict__ o3c) {
    int i = blockIdx.x * blockDim.x + threadIdx.x;
    if (i < 65536) {
        const float* W = (i < 32768) ? ws1 : wn1;
        _Float16* O = (i < 32768) ? o1s : o1n;
        int j = i & 32767;                         // 32768 = 2^15, mask ok
        int nn = j >> 7, k = j & 127;              // K=128, dout=256
        O[j] = (_Float16)W[k * 256 + nn];
    } else if (i < 196608) {
        int j = i - 65536;
        const float* W = (j < 65536) ? ws2 : wn2;
        _Float16* O = (j < 65536) ? o2s : o2n;
        j &= 65535;                                // 65536 = 2^16, mask ok
        int nn = j >> 8, k = j & 255;              // K=256, dout=256
        O[j] = (_Float16)W[k * 256 + nn];
    } else if (i < 221184) {
        int j = i - 196608;                        // [0, 24576)
        const float* W = (j < 12288) ? ws3 : wn3;
        _Float16* O = o3c + ((j < 12288) ? 0 : 12288);
        j = (j < 12288) ? j : j - 12288;           // FIX: 12288 not pow2, subtract
        int nn = j >> 8, k = j & 255;              // K=256, dout=47, npad=48
        O[j] = (nn < 47) ? (_Float16)W[k * 47 + nn] : (_Float16)0.f;
    }
}

// ---------------- mean aggregation over one 128-col fp16 plane ----------------
// Rows are 256 B. Wave per node; quarter-waves each fetch a different edge's row
// (16 lanes x 16 B = one dwordx4 per row). Depth-4/2 unroll keeps up to 4 rows
// in flight per quarter.

__global__ __launch_bounds__(256) void aggP(const _Float16* __restrict__ Xp,
                                            const int* __restrict__ csr,
                                            const int* __restrict__ offs,
                                            _Float16* __restrict__ Pp, int n) {
    int node = blockIdx.x * 4 + (threadIdx.x >> 6);
    int lane = threadIdx.x & 63;
    int qtr = lane >> 4;
    int sl = lane & 15;
    if (node >= n) return;
    int e0 = offs[node], e1 = offs[node + 1];
    float a[8] = {0.f, 0.f, 0.f, 0.f, 0.f, 0.f, 0.f, 0.f};
    int e = e0;
    for (; e + 16 <= e1; e += 16) {
        int s0 = csr[e + qtr];
        int s1 = csr[e + 4 + qtr];
        int s2 = csr[e + 8 + qtr];
        int s3 = csr[e + 12 + qtr];
        half8 u0 = ((const half8*)(Xp + (size_t)s0 * 128))[sl];
        half8 u1 = ((const half8*)(Xp + (size_t)s1 * 128))[sl];
        half8 u2 = ((const half8*)(Xp + (size_t)s2 * 128))[sl];
        half8 u3 = ((const half8*)(Xp + (size_t)s3 * 128))[sl];
        #pragma unroll
        for (int j = 0; j < 8; ++j) a[j] += (float)u0[j];
        #pragma unroll
        for (int j = 0; j < 8; ++j) a[j] += (float)u1[j];
        #pragma unroll
        for (int j = 0; j < 8; ++j) a[j] += (float)u2[j];
        #pragma unroll
        for (int j = 0; j < 8; ++j) a[j] += (float)u3[j];
    }
    for (; e + 8 <= e1; e += 8) {
        int s0 = csr[e + qtr];
        int s1 = csr[e + 4 + qtr];
        half8 u0 = ((const half8*)(Xp + (size_t)s0 * 128))[sl];
        half8 u1 = ((const half8*)(Xp + (size_t)s1 * 128))[sl];
        #pragma unroll
        for (int j = 0; j < 8; ++j) a[j] += (float)u0[j];
        #pragma unroll
        for (int j = 0; j < 8; ++j) a[j] += (float)u1[j];
    }
    for (; e + 4 <= e1; e += 4) {
        int s = csr[e + qtr];
        half8 u = ((const half8*)(Xp + (size_t)s * 128))[sl];
        #pragma unroll
        for (int j = 0; j < 8; ++j) a[j] += (float)u[j];
    }
    int rem = e1 - e;
    if (qtr < rem) {
        int s = csr[e + qtr];
        half8 u = ((const half8*)(Xp + (size_t)s * 128))[sl];
        #pragma unroll
        for (int j = 0; j < 8; ++j) a[j] += (float)u[j];
    }
    #pragma unroll
    for (int j = 0; j < 8; ++j) {
        a[j] += __shfl_xor(a[j], 16);
        a[j] += __shfl_xor(a[j], 32);
    }
    if (lane < 16) {
        float inv = 1.0f / fmaxf((float)(e1 - e0), 1.0f);
        half8 rh;
        #pragma unroll
        for (int j = 0; j < 8; ++j) rh[j] = (_Float16)(a[j] * inv);
        ((half8*)(Pp + (size_t)node * 128))[sl] = rh;
    }
}

// Layer-3 finish: out[node][0:47] = S[node] + mean(Y[nbrs]); wave per node,
// quarter-waves, 2 rows in flight per quarter; Y rows 96 B fp16.
__global__ __launch_bounds__(256) void agg_l3(const _Float16* __restrict__ Y,
                                              const float* __restrict__ S,
                                              const int* __restrict__ csr,
                                              const int* __restrict__ offs,
                                              float* __restrict__ out, int n) {
    int node = blockIdx.x * 4 + (threadIdx.x >> 6);
    int lane = threadIdx.x & 63;
    int qtr = lane >> 4;
    int sl = lane & 15;
    int c = sl < 12 ? sl : 11;
    if (node >= n) return;
    int e0 = offs[node], e1 = offs[node + 1];
    float a0 = 0.f, a1 = 0.f, a2 = 0.f, a3 = 0.f;
    int e = e0;
    for (; e + 8 <= e1; e += 8) {
        int s0 = csr[e + qtr];
        int s1 = csr[e + 4 + qtr];
        half4v f0 = ((const half4v*)(Y + (size_t)s0 * 48))[c];
        half4v f1 = ((const half4v*)(Y + (size_t)s1 * 48))[c];
        a0 += (float)f0[0] + (float)f1[0];
        a1 += (float)f0[1] + (float)f1[1];
        a2 += (float)f0[2] + (float)f1[2];
        a3 += (float)f0[3] + (float)f1[3];
    }
    for (; e + 4 <= e1; e += 4) {
        int s = csr[e + qtr];
        half4v f = ((const half4v*)(Y + (size_t)s * 48))[c];
        a0 += (float)f[0]; a1 += (float)f[1]; a2 += (float)f[2]; a3 += (float)f[3];
    }
    int rem = e1 - e;
    if (qtr < rem) {
        int s = csr[e + qtr];
        half4v f = ((const half4v*)(Y + (size_t)s * 48))[c];
        a0 += (float)f[0]; a1 += (float)f[1]; a2 += (float)f[2]; a3 += (float)f[3];
    }
    a0 += __shfl_xor(a0, 16); a0 += __shfl_xor(a0, 32);
    a1 += __shfl_xor(a1, 16); a1 += __shfl_xor(a1, 32);
    a2 += __shfl_xor(a2, 16); a2 += __shfl_xor(a2, 32);
    a3 += __shfl_xor(a3, 16); a3 += __shfl_xor(a3, 32);
    if (lane < 12) {
        float inv = 1.0f / fmaxf((float)(e1 - e0), 1.0f);
        float4 sv = ((const float4*)(S + (size_t)node * 48))[c];
        float r[4] = {sv.x + a0 * inv, sv.y + a1 * inv, sv.z + a2 * inv, sv.w + a3 * inv};
        #pragma unroll
        for (int k = 0; k < 4; ++k) {
            int col = c * 4 + k;
            if (col < 47) out[(size_t)node * 47 + col] = r[k];
        }
    }
}

// ---------------- MFMA GEMM (LDS ping-pong, no vmcnt drain) ----------------
// out[128 x dout] = A1@W1 (+ A2@W2) + b (+relu), fp32 accumulate.
// B staged in LDS (line-efficient: 64 contiguous B per thread; LDT=36
// conflict-free), DOUBLE-buffered with ONE raw barrier per k-step:
//   ds_write next-stage B -> compute current stage -> s_waitcnt lgkmcnt(0)
//   -> sched_barrier(0) -> s_barrier.
// vmcnt is NEVER drained in the loop (the __syncthreads vmcnt(0) drain was the
// r2 stall): A-ring (depth 2) and W prefetch loads stay in flight across
// barriers, consumed via compiler-counted vmcnt waits.
// Hazards: stage s writes Bs[(s+1)&1]; its prior readers (stage s-1) finished
// before their lgkmcnt(0)+barrier; its readers (stage s+1) start after the
// stage-s barrier. One barrier/stage is sufficient.
// A and (OUTFMT 1) outputs live in 128-col PLANES: element (r, k) at
// base + (k>>7)*n*128 + r*128 + (k&127).
// OUTFMT 1: fp16 plane write (dout=256). OUTFMT 2: cols 0-47 -> S fp32 (+bias),
// cols 48-95 -> Y fp16 (stride 48).

template <int NTILES, int OUTFMT>
__global__ __launch_bounds__(256, 3) void gemm_mfma(
    const _Float16* __restrict__ A1h, const _Float16* __restrict__ A2h,
    const _Float16* __restrict__ W1, const _Float16* __restrict__ W2,
    const float* __restrict__ bias, float* __restrict__ outS, _Float16* __restrict__ outY,
    _Float16* __restrict__ outh, int n, int K, int dout, int relu, int phases) {
    constexpr int NPAD = NTILES * 16;
    constexpr int LDT = 36;
    __shared__ _Float16 Bs[2][NPAD * LDT];

    const int t = threadIdx.x;
    const int bm = blockIdx.x * 128;
    const int lane = t & 63;
    const int w = t >> 6;
    const int quad = lane >> 4;
    const int tl = lane & 15;
    const int r0 = bm + w * 32 + tl;
    const int r1 = r0 + 16;
    const size_t PS = (size_t)n * 128;   // plane stride

    floatx4 acc[2][NTILES];
    #pragma unroll
    for (int i = 0; i < 2; ++i)
        #pragma unroll
        for (int j = 0; j < NTILES; ++j) acc[i][j] = (floatx4){0.f, 0.f, 0.f, 0.f};

    const int spp = K >> 5;
    const int nsteps = phases * spp;     // always even (8 or 16)

    half8 pb0, pb1, pb2, pb3;            // W regs for the NEXT stage
    half8 a0A = {0}, a1A = {0}, a0B = {0}, a1B = {0};  // A ring, depth 2

    auto wload = [&](int s2) {
        int ph2 = (s2 >= spp) ? 1 : 0;
        int k02 = (ph2 ? s2 - spp : s2) << 5;
        const _Float16* W = ph2 ? W2 : W1;
        const half8* p = (const half8*)(W + (size_t)t * K + k02);
        pb0 = p[0]; pb1 = p[1]; pb2 = p[2]; pb3 = p[3];
    };
    auto aload = [&](int s2, half8& d0, half8& d1) {
        int ph2 = (s2 >= spp) ? 1 : 0;
        int k02 = (ph2 ? s2 - spp : s2) << 5;
        const _Float16* Ah = ph2 ? A2h : A1h;
        int kq = k02 + quad * 8;
        const _Float16* Ab = Ah + ((kq >> 7) ? PS : (size_t)0) + (kq & 127);
        d0 = (half8){0}; d1 = (half8){0};
        if (r0 < n) d0 = *(const half8*)(Ab + (size_t)r0 * 128);
        if (r1 < n) d1 = *(const half8*)(Ab + (size_t)r1 * 128);
    };

    // prologue: Bs[0] <- W(0); regs <- W(1); A ring <- A(0), A(1)
    if (t < NPAD) {
        wload(0);
        *(half8*)&Bs[0][t * LDT + 0]  = pb0;
        *(half8*)&Bs[0][t * LDT + 8]  = pb1;
        *(half8*)&Bs[0][t * LDT + 16] = pb2;
        *(half8*)&Bs[0][t * LDT + 24] = pb3;
        wload(1);
    }
    aload(0, a0A, a1A);
    aload(1, a0B, a1B);
    __syncthreads();

    for (int s = 0; s < nsteps; s += 2) {
        // ---- even stage s: read Bs[0]; write Bs[1] = W(s+1); A slot A
        {
            if (s + 1 < nsteps && t < NPAD) {
                *(half8*)&Bs[1][t * LDT + 0]  = pb0;
                *(half8*)&Bs[1][t * LDT + 8]  = pb1;
                *(half8*)&Bs[1][t * LDT + 16] = pb2;
                *(half8*)&Bs[1][t * LDT + 24] = pb3;
                if (s + 2 < nsteps) wload(s + 2);
            }
            half8 ca0 = a0A, ca1 = a1A;
            if (s + 2 < nsteps) aload(s + 2, a0A, a1A);
            #pragma unroll
            for (int nt = 0; nt < NTILES; ++nt) {
                half8 bh = *(const half8*)&Bs[0][(nt * 16 + tl) * LDT + quad * 8];
                acc[0][nt] = __builtin_amdgcn_mfma_f32_16x16x32_f16(ca0, bh, acc[0][nt], 0, 0, 0);
                acc[1][nt] = __builtin_amdgcn_mfma_f32_16x16x32_f16(ca1, bh, acc[1][nt], 0, 0, 0);
            }
            asm volatile("s_waitcnt lgkmcnt(0)" ::: "memory");
            __builtin_amdgcn_sched_barrier(0);
            __builtin_amdgcn_s_barrier();
        }
        // ---- odd stage s+1: read Bs[1]; write Bs[0] = W(s+2); A slot B
        {
            int s1 = s + 1;
            if (s1 + 1 < nsteps && t < NPAD) {
                *(half8*)&Bs[0][t * LDT + 0]  = pb0;
                *(half8*)&Bs[0][t * LDT + 8]  = pb1;
                *(half8*)&Bs[0][t * LDT + 16] = pb2;
                *(half8*)&Bs[0][t * LDT + 24] = pb3;
                if (s1 + 2 < nsteps) wload(s1 + 2);
            }
            half8 ca0 = a0B, ca1 = a1B;
            if (s1 + 2 < nsteps) aload(s1 + 2, a0B, a1B);
            #pragma unroll
            for (int nt = 0; nt < NTILES; ++nt) {
                half8 bh = *(const half8*)&Bs[1][(nt * 16 + tl) * LDT + quad * 8];
                acc[0][nt] = __builtin_amdgcn_mfma_f32_16x16x32_f16(ca0, bh, acc[0][nt], 0, 0, 0);
                acc[1][nt] = __builtin_amdgcn_mfma_f32_16x16x32_f16(ca1, bh, acc[1][nt], 0, 0, 0);
            }
            asm volatile("s_waitcnt lgkmcnt(0)" ::: "memory");
            __builtin_amdgcn_sched_barrier(0);
            __builtin_amdgcn_s_barrier();
        }
    }

    #pragma unroll
    for (int mt = 0; mt < 2; ++mt) {
        #pragma unroll
        for (int nt = 0; nt < NTILES; ++nt) {
            int gc = nt * 16 + tl;
            if (OUTFMT == 1 && gc >= dout) continue;
            #pragma unroll
            for (int r = 0; r < 4; ++r) {
                int gr = bm + w * 32 + mt * 16 + quad * 4 + r;
                if (gr >= n) continue;
                float v = acc[mt][nt][r];
                if (OUTFMT == 1) {
                    v += bias[gc];
                    if (relu) v = fmaxf(v, 0.f);
                    outh[(size_t)(gc >> 7) * PS + (size_t)gr * 128 + (gc & 127)] = (_Float16)v;
                } else {
                    if (gc < 48) {
                        v += (gc < 47) ? bias[gc] : 0.f;
                        outS[(size_t)gr * 48 + gc] = v;
                    } else {
                        outY[(size_t)gr * 48 + (gc - 48)] = (_Float16)v;
                    }
                }
            }
        }
    }
}

extern "C" void kernel_launch(void* const* d_in, const int* in_sizes, int n_in,
                              void* d_out, int out_size, void* d_ws, size_t ws_size,
                              hipStream_t stream) {
    (void)in_sizes; (void)n_in; (void)out_size; (void)ws_size;
    const int N = N_NODES, E = N_EDGES;
    const float* x = (const float*)d_in[0];
    const int* src = (const int*)d_in[1];
    const int* dst = (const int*)d_in[2];
    const float* w_self1 = (const float*)d_in[3];
    const float* w_neigh1 = (const float*)d_in[4];
    const float* b1 = (const float*)d_in[5];
    const float* w_self2 = (const float*)d_in[6];
    const float* w_neigh2 = (const float*)d_in[7];
    const float* b2 = (const float*)d_in[8];
    const float* w_self3 = (const float*)d_in[9];
    const float* w_neigh3 = (const float*)d_in[10];
    const float* b3 = (const float*)d_in[11];
    float* out = (float*)d_out;

    // workspace layout (~110 MB)
    _Float16* Ph = (_Float16*)d_ws;             // N*256 fp16 (P planes P0|P1)
    _Float16* Hh = Ph + (size_t)N * 256;        // N*256 fp16 (H planes H0|H1)
    int* deg = (int*)(Hh + (size_t)N * 256);    // N
    int* offs = deg + N;                        // N+4
    int* csr = offs + N + 4;                    // E
    _Float16* wbuf = (_Float16*)(csr + E);
    _Float16* w1s = wbuf;                       // 256*128
    _Float16* w1n = w1s + 32768;                // 256*128
    _Float16* w2s = w1n + 32768;                // 256*256
    _Float16* w2n = w2s + 65536;                // 256*256
    _Float16* w3c = w2n + 65536;                // 96*256 combined [self|neigh]
    int* bsum = (int*)(w3c + 24576);            // 64
    int* bbase = bsum + 64;                     // NB+1
    // overlays on the Ph region:
    int* rank = (int*)Ph;                       // E ints, dead before aggP writes P0
    _Float16* xh = Ph + (size_t)N * 128;        // N*128 fp16 (layer 1; dead after gemm1)
    float* S = (float*)Ph;                      // N*48 fp32 (layer 3; P dead)
    _Float16* Y = (_Float16*)(S + (size_t)N * 48);  // N*48 fp16

    const int NB = (N + 2047) / 2048;           // 49 scan blocks

    hipMemsetAsync(deg, 0, N * sizeof(int), stream);
    deg_rank<<<(E + 255) / 256, 256, 0, stream>>>(dst, deg, rank, E);
    scan_partial<<<NB, 256, 0, stream>>>(deg, bsum, N);
    scan_blocksums<<<1, 64, 0, stream>>>(bsum, bbase, NB);
    scan_write<<<NB, 256, 0, stream>>>(deg, bbase, offs, N, NB);
    fill_csr2<<<(E + 255) / 256, 256, 0, stream>>>(src, dst, offs, rank, csr, E);

    cvt_f16<<<(N * 128 / 4 + 255) / 256, 256, 0, stream>>>((const float4*)x, (half4v*)xh,
                                                           N * 128 / 4);
    prep_all<<<(221184 + 255) / 256, 256, 0, stream>>>(w_self1, w_neigh1, w_self2, w_neigh2,
                                                       w_self3, w_neigh3, w1s, w1n, w2s, w2n,
                                                       w3c);

    int gemmGrid = (N + 127) / 128;
    int aggGrid = (N + 3) / 4;

    // layer 1: 128 -> 256, relu.  H planes = fp16(relu(x@Ws1 + P@Wn1 + b1))
    aggP<<<aggGrid, 256, 0, stream>>>(xh, csr, offs, Ph, N);
    gemm_mfma<16, 1><<<gemmGrid, 256, 0, stream>>>(xh, Ph, w1s, w1n, b1, nullptr, nullptr,
                                                   Hh, N, 128, 256, 1, 2);
    // layer 2: 256 -> 256, relu, in place.  Aggregate each H plane separately
    // (temporal split halves the concurrent gather footprint for L2 locality).
    aggP<<<aggGrid, 256, 0, stream>>>(Hh, csr, offs, Ph, N);
    aggP<<<aggGrid, 256, 0, stream>>>(Hh + (size_t)N * 128, csr, offs, Ph + (size_t)N * 128, N);
    gemm_mfma<16, 1><<<gemmGrid, 256, 0, stream>>>(Hh, Ph, w2s, w2n, b2, nullptr, nullptr,
                                                   Hh, N, 256, 256, 1, 2);
    // layer 3: S = H@Ws3+b3 (fp32), Y = H@Wn3 (fp16) in one dual GEMM, then
    // out = S + mean-agg(Y).
    gemm_mfma<6, 2><<<gemmGrid, 256, 0, stream>>>(Hh, nullptr, w3c, nullptr, b3, S, Y,
                                                  nullptr, N, 256, 96, 0, 1);
    agg_l3<<<aggGrid, 256, 0, stream>>>(Y, S, csr, offs, out, N);
}

// Round 5
// 643.705 us; speedup vs baseline: 1.2140x; 1.2140x over previous
//
#include <hip/hip_runtime.h>

#define N_NODES 100000
#define N_EDGES 1600000

typedef __attribute__((ext_vector_type(8))) _Float16 half8;
typedef __attribute__((ext_vector_type(4))) _Float16 half4v;
typedef __attribute__((ext_vector_type(4))) float floatx4;

// ---------------- CSR build ----------------
// Pass 1: degree count + per-edge rank (removes atomics from the fill pass).

__global__ void deg_rank(const int* __restrict__ dst, int* __restrict__ deg,
                         int* __restrict__ rank, int e) {
    int i = blockIdx.x * blockDim.x + threadIdx.x;
    if (i < e) rank[i] = atomicAdd(&deg[dst[i]], 1);
}

// Multi-block exclusive scan of deg -> offs. Chunk = 2048/block. NB = 49.

__global__ __launch_bounds__(256) void scan_partial(const int* __restrict__ deg,
                                                    int* __restrict__ bsum, int n) {
    __shared__ int wsum[4];
    int t = threadIdx.x;
    int base = blockIdx.x * 2048 + t * 8;
    int tsum = 0;
    #pragma unroll
    for (int k = 0; k < 8; ++k) {
        int idx = base + k;
        tsum += (idx < n) ? deg[idx] : 0;
    }
    #pragma unroll
    for (int d = 1; d < 64; d <<= 1) tsum += __shfl_xor(tsum, d, 64);
    if ((t & 63) == 0) wsum[t >> 6] = tsum;
    __syncthreads();
    if (t == 0) bsum[blockIdx.x] = wsum[0] + wsum[1] + wsum[2] + wsum[3];
}

__global__ void scan_blocksums(const int* __restrict__ bsum, int* __restrict__ bbase, int nb) {
    int t = threadIdx.x;               // 64 threads
    int v = (t < nb) ? bsum[t] : 0;
    int s = v;
    #pragma unroll
    for (int d = 1; d < 64; d <<= 1) {
        int u = __shfl_up(s, d, 64);
        if (t >= d) s += u;
    }
    if (t < nb) bbase[t] = s - v;
    if (t == 63) bbase[nb] = s;
}

__global__ __launch_bounds__(256) void scan_write(const int* __restrict__ deg,
                                                  const int* __restrict__ bbase,
                                                  int* __restrict__ offs, int n, int nb) {
    __shared__ int wsum[4];
    int t = threadIdx.x;
    int lane = t & 63, w = t >> 6;
    int base = blockIdx.x * 2048 + t * 8;
    int v[8];
    #pragma unroll
    for (int k = 0; k < 8; ++k) {
        int idx = base + k;
        v[k] = (idx < n) ? deg[idx] : 0;
    }
    int tsum = 0;
    #pragma unroll
    for (int k = 0; k < 8; ++k) { int x = v[k]; v[k] = tsum; tsum += x; }
    int s = tsum;
    #pragma unroll
    for (int d = 1; d < 64; d <<= 1) {
        int u = __shfl_up(s, d, 64);
        if (lane >= d) s += u;
    }
    if (lane == 63) wsum[w] = s;
    __syncthreads();
    int wb = 0;
    for (int j = 0; j < w; ++j) wb += wsum[j];
    int texcl = bbase[blockIdx.x] + wb + (s - tsum);
    #pragma unroll
    for (int k = 0; k < 8; ++k) {
        int idx = base + k;
        if (idx < n) offs[idx] = texcl + v[k];
    }
    if (blockIdx.x == 0 && t == 0) offs[n] = bbase[nb];
}

// Pass 2: atomic-free CSR fill using precomputed ranks.
__global__ void fill_csr2(const int* __restrict__ src, const int* __restrict__ dst,
                          const int* __restrict__ offs, const int* __restrict__ rank,
                          int* __restrict__ csr, int e) {
    int i = blockIdx.x * blockDim.x + threadIdx.x;
    if (i < e) csr[offs[dst[i]] + rank[i]] = src[i];
}

// ---------------- x -> fp16 convert ----------------

__global__ void cvt_f16(const float4* __restrict__ in, half4v* __restrict__ oh, int n4) {
    int i = blockIdx.x * blockDim.x + threadIdx.x;
    if (i >= n4) return;
    float4 v = in[i];
    half4v h;
    h[0] = (_Float16)v.x; h[1] = (_Float16)v.y;
    h[2] = (_Float16)v.z; h[3] = (_Float16)v.w;
    oh[i] = h;
}

// ---------------- fused weight prep (all 6 weights, one launch) ----------------
// W[K][dout] fp32 -> Wt[npad][K] fp16.
// NOTE: 12288 is NOT a power of two -- use subtraction, never masking (r8 bug).

__global__ void prep_all(const float* __restrict__ ws1, const float* __restrict__ wn1,
                         const float* __restrict__ ws2, const float* __restrict__ wn2,
                         const float* __restrict__ ws3, const float* __restrict__ wn3,
                         _Float16* __restrict__ o1s, _Float16* __restrict__ o1n,
                         _Float16* __restrict__ o2s, _Float16* __restrict__ o2n,
                         _Float16* __restrict__ o3c) {
    int i = blockIdx.x * blockDim.x + threadIdx.x;
    if (i < 65536) {
        const float* W = (i < 32768) ? ws1 : wn1;
        _Float16* O = (i < 32768) ? o1s : o1n;
        int j = i & 32767;                         // 32768 = 2^15, mask ok
        int nn = j >> 7, k = j & 127;              // K=128, dout=256
        O[j] = (_Float16)W[k * 256 + nn];
    } else if (i < 196608) {
        int j = i - 65536;
        const float* W = (j < 65536) ? ws2 : wn2;
        _Float16* O = (j < 65536) ? o2s : o2n;
        j &= 65535;                                // 65536 = 2^16, mask ok
        int nn = j >> 8, k = j & 255;              // K=256, dout=256
        O[j] = (_Float16)W[k * 256 + nn];
    } else if (i < 221184) {
        int j = i - 196608;                        // [0, 24576)
        const float* W = (j < 12288) ? ws3 : wn3;
        _Float16* O = o3c + ((j < 12288) ? 0 : 12288);
        j = (j < 12288) ? j : j - 12288;           // FIX: 12288 not pow2, subtract
        int nn = j >> 8, k = j & 255;              // K=256, dout=47, npad=48
        O[j] = (nn < 47) ? (_Float16)W[k * 47 + nn] : (_Float16)0.f;
    }
}

// ---------------- mean aggregation over one 128-col fp16 plane ----------------
// Rows are 256 B. Wave per node; quarter-waves each fetch a different edge's row
// (16 lanes x 16 B = one dwordx4 per row). Depth-4/2 unroll keeps up to 4 rows
// in flight per quarter.

__global__ __launch_bounds__(256) void aggP(const _Float16* __restrict__ Xp,
                                            const int* __restrict__ csr,
                                            const int* __restrict__ offs,
                                            _Float16* __restrict__ Pp, int n) {
    int node = blockIdx.x * 4 + (threadIdx.x >> 6);
    int lane = threadIdx.x & 63;
    int qtr = lane >> 4;
    int sl = lane & 15;
    if (node >= n) return;
    int e0 = offs[node], e1 = offs[node + 1];
    float a[8] = {0.f, 0.f, 0.f, 0.f, 0.f, 0.f, 0.f, 0.f};
    int e = e0;
    for (; e + 16 <= e1; e += 16) {
        int s0 = csr[e + qtr];
        int s1 = csr[e + 4 + qtr];
        int s2 = csr[e + 8 + qtr];
        int s3 = csr[e + 12 + qtr];
        half8 u0 = ((const half8*)(Xp + (size_t)s0 * 128))[sl];
        half8 u1 = ((const half8*)(Xp + (size_t)s1 * 128))[sl];
        half8 u2 = ((const half8*)(Xp + (size_t)s2 * 128))[sl];
        half8 u3 = ((const half8*)(Xp + (size_t)s3 * 128))[sl];
        #pragma unroll
        for (int j = 0; j < 8; ++j) a[j] += (float)u0[j];
        #pragma unroll
        for (int j = 0; j < 8; ++j) a[j] += (float)u1[j];
        #pragma unroll
        for (int j = 0; j < 8; ++j) a[j] += (float)u2[j];
        #pragma unroll
        for (int j = 0; j < 8; ++j) a[j] += (float)u3[j];
    }
    for (; e + 8 <= e1; e += 8) {
        int s0 = csr[e + qtr];
        int s1 = csr[e + 4 + qtr];
        half8 u0 = ((const half8*)(Xp + (size_t)s0 * 128))[sl];
        half8 u1 = ((const half8*)(Xp + (size_t)s1 * 128))[sl];
        #pragma unroll
        for (int j = 0; j < 8; ++j) a[j] += (float)u0[j];
        #pragma unroll
        for (int j = 0; j < 8; ++j) a[j] += (float)u1[j];
    }
    for (; e + 4 <= e1; e += 4) {
        int s = csr[e + qtr];
        half8 u = ((const half8*)(Xp + (size_t)s * 128))[sl];
        #pragma unroll
        for (int j = 0; j < 8; ++j) a[j] += (float)u[j];
    }
    int rem = e1 - e;
    if (qtr < rem) {
        int s = csr[e + qtr];
        half8 u = ((const half8*)(Xp + (size_t)s * 128))[sl];
        #pragma unroll
        for (int j = 0; j < 8; ++j) a[j] += (float)u[j];
    }
    #pragma unroll
    for (int j = 0; j < 8; ++j) {
        a[j] += __shfl_xor(a[j], 16);
        a[j] += __shfl_xor(a[j], 32);
    }
    if (lane < 16) {
        float inv = 1.0f / fmaxf((float)(e1 - e0), 1.0f);
        half8 rh;
        #pragma unroll
        for (int j = 0; j < 8; ++j) rh[j] = (_Float16)(a[j] * inv);
        ((half8*)(Pp + (size_t)node * 128))[sl] = rh;
    }
}

// Layer-3 finish: out[node][0:47] = S[node] + mean(Y[nbrs]); wave per node,
// quarter-waves, 2 rows in flight per quarter; Y rows 96 B fp16.
__global__ __launch_bounds__(256) void agg_l3(const _Float16* __restrict__ Y,
                                              const float* __restrict__ S,
                                              const int* __restrict__ csr,
                                              const int* __restrict__ offs,
                                              float* __restrict__ out, int n) {
    int node = blockIdx.x * 4 + (threadIdx.x >> 6);
    int lane = threadIdx.x & 63;
    int qtr = lane >> 4;
    int sl = lane & 15;
    int c = sl < 12 ? sl : 11;
    if (node >= n) return;
    int e0 = offs[node], e1 = offs[node + 1];
    float a0 = 0.f, a1 = 0.f, a2 = 0.f, a3 = 0.f;
    int e = e0;
    for (; e + 8 <= e1; e += 8) {
        int s0 = csr[e + qtr];
        int s1 = csr[e + 4 + qtr];
        half4v f0 = ((const half4v*)(Y + (size_t)s0 * 48))[c];
        half4v f1 = ((const half4v*)(Y + (size_t)s1 * 48))[c];
        a0 += (float)f0[0] + (float)f1[0];
        a1 += (float)f0[1] + (float)f1[1];
        a2 += (float)f0[2] + (float)f1[2];
        a3 += (float)f0[3] + (float)f1[3];
    }
    for (; e + 4 <= e1; e += 4) {
        int s = csr[e + qtr];
        half4v f = ((const half4v*)(Y + (size_t)s * 48))[c];
        a0 += (float)f[0]; a1 += (float)f[1]; a2 += (float)f[2]; a3 += (float)f[3];
    }
    int rem = e1 - e;
    if (qtr < rem) {
        int s = csr[e + qtr];
        half4v f = ((const half4v*)(Y + (size_t)s * 48))[c];
        a0 += (float)f[0]; a1 += (float)f[1]; a2 += (float)f[2]; a3 += (float)f[3];
    }
    a0 += __shfl_xor(a0, 16); a0 += __shfl_xor(a0, 32);
    a1 += __shfl_xor(a1, 16); a1 += __shfl_xor(a1, 32);
    a2 += __shfl_xor(a2, 16); a2 += __shfl_xor(a2, 32);
    a3 += __shfl_xor(a3, 16); a3 += __shfl_xor(a3, 32);
    if (lane < 12) {
        float inv = 1.0f / fmaxf((float)(e1 - e0), 1.0f);
        float4 sv = ((const float4*)(S + (size_t)node * 48))[c];
        float r[4] = {sv.x + a0 * inv, sv.y + a1 * inv, sv.z + a2 * inv, sv.w + a3 * inv};
        #pragma unroll
        for (int k = 0; k < 4; ++k) {
            int col = c * 4 + k;
            if (col < 47) out[(size_t)node * 47 + col] = r[k];
        }
    }
}

// ---------------- MFMA GEMM (LDS ping-pong, no vmcnt drain) ----------------
// out[128 x dout] = A1@W1 (+ A2@W2) + b (+relu), fp32 accumulate.
// B staged in LDS (LDT=36, conflict-free), DOUBLE-buffered with ONE raw
// barrier per k-step: ds_write next-stage B -> compute current -> s_waitcnt
// lgkmcnt(0) -> sched_barrier(0) -> s_barrier. vmcnt is NEVER drained in the
// loop: A-ring (depth 2) and W prefetch loads stay in flight across barriers,
// consumed via compiler-counted vmcnt waits.
// __launch_bounds__(256, 2): acc[2][16] = 128 AGPR + ~96 VGPR = 224 <= 256
// per wave at 2 waves/SIMD. (256,3) in r4 capped at 170 -> spilled acc to
// scratch (WRITE_SIZE 50->262 MB, dur 108->195 us). DO NOT raise to 3 at this
// accumulator footprint.
// A and (OUTFMT 1) outputs live in 128-col PLANES: element (r, k) at
// base + (k>>7)*n*128 + r*128 + (k&127).
// OUTFMT 1: fp16 plane write (dout=256). OUTFMT 2: cols 0-47 -> S fp32 (+bias),
// cols 48-95 -> Y fp16 (stride 48).

template <int NTILES, int OUTFMT>
__global__ __launch_bounds__(256, 2) void gemm_mfma(
    const _Float16* __restrict__ A1h, const _Float16* __restrict__ A2h,
    const _Float16* __restrict__ W1, const _Float16* __restrict__ W2,
    const float* __restrict__ bias, float* __restrict__ outS, _Float16* __restrict__ outY,
    _Float16* __restrict__ outh, int n, int K, int dout, int relu, int phases) {
    constexpr int NPAD = NTILES * 16;
    constexpr int LDT = 36;
    __shared__ _Float16 Bs[2][NPAD * LDT];

    const int t = threadIdx.x;
    const int bm = blockIdx.x * 128;
    const int lane = t & 63;
    const int w = t >> 6;
    const int quad = lane >> 4;
    const int tl = lane & 15;
    const int r0 = bm + w * 32 + tl;
    const int r1 = r0 + 16;
    const size_t PS = (size_t)n * 128;   // plane stride

    floatx4 acc[2][NTILES];
    #pragma unroll
    for (int i = 0; i < 2; ++i)
        #pragma unroll
        for (int j = 0; j < NTILES; ++j) acc[i][j] = (floatx4){0.f, 0.f, 0.f, 0.f};

    const int spp = K >> 5;
    const int nsteps = phases * spp;     // always even (8 or 16)

    half8 pb0, pb1, pb2, pb3;            // W regs for the NEXT stage
    half8 a0A = {0}, a1A = {0}, a0B = {0}, a1B = {0};  // A ring, depth 2

    auto wload = [&](int s2) {
        int ph2 = (s2 >= spp) ? 1 : 0;
        int k02 = (ph2 ? s2 - spp : s2) << 5;
        const _Float16* W = ph2 ? W2 : W1;
        const half8* p = (const half8*)(W + (size_t)t * K + k02);
        pb0 = p[0]; pb1 = p[1]; pb2 = p[2]; pb3 = p[3];
    };
    auto aload = [&](int s2, half8& d0, half8& d1) {
        int ph2 = (s2 >= spp) ? 1 : 0;
        int k02 = (ph2 ? s2 - spp : s2) << 5;
        const _Float16* Ah = ph2 ? A2h : A1h;
        int kq = k02 + quad * 8;
        const _Float16* Ab = Ah + ((kq >> 7) ? PS : (size_t)0) + (kq & 127);
        d0 = (half8){0}; d1 = (half8){0};
        if (r0 < n) d0 = *(const half8*)(Ab + (size_t)r0 * 128);
        if (r1 < n) d1 = *(const half8*)(Ab + (size_t)r1 * 128);
    };

    // prologue: Bs[0] <- W(0); regs <- W(1); A ring <- A(0), A(1)
    if (t < NPAD) {
        wload(0);
        *(half8*)&Bs[0][t * LDT + 0]  = pb0;
        *(half8*)&Bs[0][t * LDT + 8]  = pb1;
        *(half8*)&Bs[0][t * LDT + 16] = pb2;
        *(half8*)&Bs[0][t * LDT + 24] = pb3;
        wload(1);
    }
    aload(0, a0A, a1A);
    aload(1, a0B, a1B);
    __syncthreads();

    for (int s = 0; s < nsteps; s += 2) {
        // ---- even stage s: read Bs[0]; write Bs[1] = W(s+1); A slot A
        {
            if (s + 1 < nsteps && t < NPAD) {
                *(half8*)&Bs[1][t * LDT + 0]  = pb0;
                *(half8*)&Bs[1][t * LDT + 8]  = pb1;
                *(half8*)&Bs[1][t * LDT + 16] = pb2;
                *(half8*)&Bs[1][t * LDT + 24] = pb3;
                if (s + 2 < nsteps) wload(s + 2);
            }
            half8 ca0 = a0A, ca1 = a1A;
            if (s + 2 < nsteps) aload(s + 2, a0A, a1A);
            #pragma unroll
            for (int nt = 0; nt < NTILES; ++nt) {
                half8 bh = *(const half8*)&Bs[0][(nt * 16 + tl) * LDT + quad * 8];
                acc[0][nt] = __builtin_amdgcn_mfma_f32_16x16x32_f16(ca0, bh, acc[0][nt], 0, 0, 0);
                acc[1][nt] = __builtin_amdgcn_mfma_f32_16x16x32_f16(ca1, bh, acc[1][nt], 0, 0, 0);
            }
            asm volatile("s_waitcnt lgkmcnt(0)" ::: "memory");
            __builtin_amdgcn_sched_barrier(0);
            __builtin_amdgcn_s_barrier();
        }
        // ---- odd stage s+1: read Bs[1]; write Bs[0] = W(s+2); A slot B
        {
            int s1 = s + 1;
            if (s1 + 1 < nsteps && t < NPAD) {
                *(half8*)&Bs[0][t * LDT + 0]  = pb0;
                *(half8*)&Bs[0][t * LDT + 8]  = pb1;
                *(half8*)&Bs[0][t * LDT + 16] = pb2;
                *(half8*)&Bs[0][t * LDT + 24] = pb3;
                if (s1 + 2 < nsteps) wload(s1 + 2);
            }
            half8 ca0 = a0B, ca1 = a1B;
            if (s1 + 2 < nsteps) aload(s1 + 2, a0B, a1B);
            #pragma unroll
            for (int nt = 0; nt < NTILES; ++nt) {
                half8 bh = *(const half8*)&Bs[1][(nt * 16 + tl) * LDT + quad * 8];
                acc[0][nt] = __builtin_amdgcn_mfma_f32_16x16x32_f16(ca0, bh, acc[0][nt], 0, 0, 0);
                acc[1][nt] = __builtin_amdgcn_mfma_f32_16x16x32_f16(ca1, bh, acc[1][nt], 0, 0, 0);
            }
            asm volatile("s_waitcnt lgkmcnt(0)" ::: "memory");
            __builtin_amdgcn_sched_barrier(0);
            __builtin_amdgcn_s_barrier();
        }
    }

    #pragma unroll
    for (int mt = 0; mt < 2; ++mt) {
        #pragma unroll
        for (int nt = 0; nt < NTILES; ++nt) {
            int gc = nt * 16 + tl;
            if (OUTFMT == 1 && gc >= dout) continue;
            #pragma unroll
            for (int r = 0; r < 4; ++r) {
                int gr = bm + w * 32 + mt * 16 + quad * 4 + r;
                if (gr >= n) continue;
                float v = acc[mt][nt][r];
                if (OUTFMT == 1) {
                    v += bias[gc];
                    if (relu) v = fmaxf(v, 0.f);
                    outh[(size_t)(gc >> 7) * PS + (size_t)gr * 128 + (gc & 127)] = (_Float16)v;
                } else {
                    if (gc < 48) {
                        v += (gc < 47) ? bias[gc] : 0.f;
                        outS[(size_t)gr * 48 + gc] = v;
                    } else {
                        outY[(size_t)gr * 48 + (gc - 48)] = (_Float16)v;
                    }
                }
            }
        }
    }
}

extern "C" void kernel_launch(void* const* d_in, const int* in_sizes, int n_in,
                              void* d_out, int out_size, void* d_ws, size_t ws_size,
                              hipStream_t stream) {
    (void)in_sizes; (void)n_in; (void)out_size; (void)ws_size;
    const int N = N_NODES, E = N_EDGES;
    const float* x = (const float*)d_in[0];
    const int* src = (const int*)d_in[1];
    const int* dst = (const int*)d_in[2];
    const float* w_self1 = (const float*)d_in[3];
    const float* w_neigh1 = (const float*)d_in[4];
    const float* b1 = (const float*)d_in[5];
    const float* w_self2 = (const float*)d_in[6];
    const float* w_neigh2 = (const float*)d_in[7];
    const float* b2 = (const float*)d_in[8];
    const float* w_self3 = (const float*)d_in[9];
    const float* w_neigh3 = (const float*)d_in[10];
    const float* b3 = (const float*)d_in[11];
    float* out = (float*)d_out;

    // workspace layout (~110 MB)
    _Float16* Ph = (_Float16*)d_ws;             // N*256 fp16 (P planes P0|P1)
    _Float16* Hh = Ph + (size_t)N * 256;        // N*256 fp16 (H planes H0|H1)
    int* deg = (int*)(Hh + (size_t)N * 256);    // N
    int* offs = deg + N;                        // N+4
    int* csr = offs + N + 4;                    // E
    _Float16* wbuf = (_Float16*)(csr + E);
    _Float16* w1s = wbuf;                       // 256*128
    _Float16* w1n = w1s + 32768;                // 256*128
    _Float16* w2s = w1n + 32768;                // 256*256
    _Float16* w2n = w2s + 65536;                // 256*256
    _Float16* w3c = w2n + 65536;                // 96*256 combined [self|neigh]
    int* bsum = (int*)(w3c + 24576);            // 64
    int* bbase = bsum + 64;                     // NB+1
    // overlays on the Ph region:
    int* rank = (int*)Ph;                       // E ints, dead before aggP writes P0
    _Float16* xh = Ph + (size_t)N * 128;        // N*128 fp16 (layer 1; dead after gemm1)
    float* S = (float*)Ph;                      // N*48 fp32 (layer 3; P dead)
    _Float16* Y = (_Float16*)(S + (size_t)N * 48);  // N*48 fp16

    const int NB = (N + 2047) / 2048;           // 49 scan blocks

    hipMemsetAsync(deg, 0, N * sizeof(int), stream);
    deg_rank<<<(E + 255) / 256, 256, 0, stream>>>(dst, deg, rank, E);
    scan_partial<<<NB, 256, 0, stream>>>(deg, bsum, N);
    scan_blocksums<<<1, 64, 0, stream>>>(bsum, bbase, NB);
    scan_write<<<NB, 256, 0, stream>>>(deg, bbase, offs, N, NB);
    fill_csr2<<<(E + 255) / 256, 256, 0, stream>>>(src, dst, offs, rank, csr, E);

    cvt_f16<<<(N * 128 / 4 + 255) / 256, 256, 0, stream>>>((const float4*)x, (half4v*)xh,
                                                           N * 128 / 4);
    prep_all<<<(221184 + 255) / 256, 256, 0, stream>>>(w_self1, w_neigh1, w_self2, w_neigh2,
                                                       w_self3, w_neigh3, w1s, w1n, w2s, w2n,
                                                       w3c);

    int gemmGrid = (N + 127) / 128;
    int aggGrid = (N + 3) / 4;

    // layer 1: 128 -> 256, relu.  H planes = fp16(relu(x@Ws1 + P@Wn1 + b1))
    aggP<<<aggGrid, 256, 0, stream>>>(xh, csr, offs, Ph, N);
    gemm_mfma<16, 1><<<gemmGrid, 256, 0, stream>>>(xh, Ph, w1s, w1n, b1, nullptr, nullptr,
                                                   Hh, N, 128, 256, 1, 2);
    // layer 2: 256 -> 256, relu, in place.  Aggregate each H plane separately
    // (temporal split halves the concurrent gather footprint for L2 locality).
    aggP<<<aggGrid, 256, 0, stream>>>(Hh, csr, offs, Ph, N);
    aggP<<<aggGrid, 256, 0, stream>>>(Hh + (size_t)N * 128, csr, offs, Ph + (size_t)N * 128, N);
    gemm_mfma<16, 1><<<gemmGrid, 256, 0, stream>>>(Hh, Ph, w2s, w2n, b2, nullptr, nullptr,
                                                   Hh, N, 256, 256, 1, 2);
    // layer 3: S = H@Ws3+b3 (fp32), Y = H@Wn3 (fp16) in one dual GEMM, then
    // out = S + mean-agg(Y).
    gemm_mfma<6, 2><<<gemmGrid, 256, 0, stream>>>(Hh, nullptr, w3c, nullptr, b3, S, Y,
                                                  nullptr, N, 256, 96, 0, 1);
    agg_l3<<<aggGrid, 256, 0, stream>>>(Y, S, csr, offs, out, N);
}

// Round 6
// 601.000 us; speedup vs baseline: 1.3003x; 1.0711x over previous
//
#include <hip/hip_runtime.h>

#define N_NODES 100000
#define N_EDGES 1600000

typedef __attribute__((ext_vector_type(8))) _Float16 half8;
typedef __attribute__((ext_vector_type(4))) _Float16 half4v;
typedef __attribute__((ext_vector_type(4))) float floatx4;

// ---------------- CSR build ----------------

__global__ void deg_rank(const int* __restrict__ dst, int* __restrict__ deg,
                         int* __restrict__ rank, int e) {
    int i = blockIdx.x * blockDim.x + threadIdx.x;
    if (i < e) rank[i] = atomicAdd(&deg[dst[i]], 1);
}

__global__ __launch_bounds__(256) void scan_partial(const int* __restrict__ deg,
                                                    int* __restrict__ bsum, int n) {
    __shared__ int wsum[4];
    int t = threadIdx.x;
    int base = blockIdx.x * 2048 + t * 8;
    int tsum = 0;
    #pragma unroll
    for (int k = 0; k < 8; ++k) {
        int idx = base + k;
        tsum += (idx < n) ? deg[idx] : 0;
    }
    #pragma unroll
    for (int d = 1; d < 64; d <<= 1) tsum += __shfl_xor(tsum, d, 64);
    if ((t & 63) == 0) wsum[t >> 6] = tsum;
    __syncthreads();
    if (t == 0) bsum[blockIdx.x] = wsum[0] + wsum[1] + wsum[2] + wsum[3];
}

__global__ void scan_blocksums(const int* __restrict__ bsum, int* __restrict__ bbase, int nb) {
    int t = threadIdx.x;               // 64 threads
    int v = (t < nb) ? bsum[t] : 0;
    int s = v;
    #pragma unroll
    for (int d = 1; d < 64; d <<= 1) {
        int u = __shfl_up(s, d, 64);
        if (t >= d) s += u;
    }
    if (t < nb) bbase[t] = s - v;
    if (t == 63) bbase[nb] = s;
}

__global__ __launch_bounds__(256) void scan_write(const int* __restrict__ deg,
                                                  const int* __restrict__ bbase,
                                                  int* __restrict__ offs, int n, int nb) {
    __shared__ int wsum[4];
    int t = threadIdx.x;
    int lane = t & 63, w = t >> 6;
    int base = blockIdx.x * 2048 + t * 8;
    int v[8];
    #pragma unroll
    for (int k = 0; k < 8; ++k) {
        int idx = base + k;
        v[k] = (idx < n) ? deg[idx] : 0;
    }
    int tsum = 0;
    #pragma unroll
    for (int k = 0; k < 8; ++k) { int x = v[k]; v[k] = tsum; tsum += x; }
    int s = tsum;
    #pragma unroll
    for (int d = 1; d < 64; d <<= 1) {
        int u = __shfl_up(s, d, 64);
        if (lane >= d) s += u;
    }
    if (lane == 63) wsum[w] = s;
    __syncthreads();
    int wb = 0;
    for (int j = 0; j < w; ++j) wb += wsum[j];
    int texcl = bbase[blockIdx.x] + wb + (s - tsum);
    #pragma unroll
    for (int k = 0; k < 8; ++k) {
        int idx = base + k;
        if (idx < n) offs[idx] = texcl + v[k];
    }
    if (blockIdx.x == 0 && t == 0) offs[n] = bbase[nb];
}

__global__ void fill_csr2(const int* __restrict__ src, const int* __restrict__ dst,
                          const int* __restrict__ offs, const int* __restrict__ rank,
                          int* __restrict__ csr, int e) {
    int i = blockIdx.x * blockDim.x + threadIdx.x;
    if (i < e) csr[offs[dst[i]] + rank[i]] = src[i];
}

// ---------------- x -> fp16 convert ----------------

__global__ void cvt_f16(const float4* __restrict__ in, half4v* __restrict__ oh, int n4) {
    int i = blockIdx.x * blockDim.x + threadIdx.x;
    if (i >= n4) return;
    float4 v = in[i];
    half4v h;
    h[0] = (_Float16)v.x; h[1] = (_Float16)v.y;
    h[2] = (_Float16)v.z; h[3] = (_Float16)v.w;
    oh[i] = h;
}

// ---------------- fused weight prep (all 6 weights, one launch) ----------------
// W[K][dout] fp32 -> Wt[npad][K] fp16.
// NOTE: 12288 is NOT a power of two -- use subtraction, never masking (r8 bug).

__global__ void prep_all(const float* __restrict__ ws1, const float* __restrict__ wn1,
                         const float* __restrict__ ws2, const float* __restrict__ wn2,
                         const float* __restrict__ ws3, const float* __restrict__ wn3,
                         _Float16* __restrict__ o1s, _Float16* __restrict__ o1n,
                         _Float16* __restrict__ o2s, _Float16* __restrict__ o2n,
                         _Float16* __restrict__ o3c) {
    int i = blockIdx.x * blockDim.x + threadIdx.x;
    if (i < 65536) {
        const float* W = (i < 32768) ? ws1 : wn1;
        _Float16* O = (i < 32768) ? o1s : o1n;
        int j = i & 32767;                         // 32768 = 2^15, mask ok
        int nn = j >> 7, k = j & 127;              // K=128, dout=256
        O[j] = (_Float16)W[k * 256 + nn];
    } else if (i < 196608) {
        int j = i - 65536;
        const float* W = (j < 65536) ? ws2 : wn2;
        _Float16* O = (j < 65536) ? o2s : o2n;
        j &= 65535;                                // 65536 = 2^16, mask ok
        int nn = j >> 8, k = j & 255;              // K=256, dout=256
        O[j] = (_Float16)W[k * 256 + nn];
    } else if (i < 221184) {
        int j = i - 196608;                        // [0, 24576)
        const float* W = (j < 12288) ? ws3 : wn3;
        _Float16* O = o3c + ((j < 12288) ? 0 : 12288);
        j = (j < 12288) ? j : j - 12288;           // FIX: 12288 not pow2, subtract
        int nn = j >> 8, k = j & 255;              // K=256, dout=47, npad=48
        O[j] = (nn < 47) ? (_Float16)W[k * 47 + nn] : (_Float16)0.f;
    }
}

// ---------------- mean aggregation over one 128-col fp16 plane ----------------

__global__ __launch_bounds__(256) void aggP(const _Float16* __restrict__ Xp,
                                            const int* __restrict__ csr,
                                            const int* __restrict__ offs,
                                            _Float16* __restrict__ Pp, int n) {
    int node = blockIdx.x * 4 + (threadIdx.x >> 6);
    int lane = threadIdx.x & 63;
    int qtr = lane >> 4;
    int sl = lane & 15;
    if (node >= n) return;
    int e0 = offs[node], e1 = offs[node + 1];
    float a[8] = {0.f, 0.f, 0.f, 0.f, 0.f, 0.f, 0.f, 0.f};
    int e = e0;
    for (; e + 16 <= e1; e += 16) {
        int s0 = csr[e + qtr];
        int s1 = csr[e + 4 + qtr];
        int s2 = csr[e + 8 + qtr];
        int s3 = csr[e + 12 + qtr];
        half8 u0 = ((const half8*)(Xp + (size_t)s0 * 128))[sl];
        half8 u1 = ((const half8*)(Xp + (size_t)s1 * 128))[sl];
        half8 u2 = ((const half8*)(Xp + (size_t)s2 * 128))[sl];
        half8 u3 = ((const half8*)(Xp + (size_t)s3 * 128))[sl];
        #pragma unroll
        for (int j = 0; j < 8; ++j) a[j] += (float)u0[j];
        #pragma unroll
        for (int j = 0; j < 8; ++j) a[j] += (float)u1[j];
        #pragma unroll
        for (int j = 0; j < 8; ++j) a[j] += (float)u2[j];
        #pragma unroll
        for (int j = 0; j < 8; ++j) a[j] += (float)u3[j];
    }
    for (; e + 8 <= e1; e += 8) {
        int s0 = csr[e + qtr];
        int s1 = csr[e + 4 + qtr];
        half8 u0 = ((const half8*)(Xp + (size_t)s0 * 128))[sl];
        half8 u1 = ((const half8*)(Xp + (size_t)s1 * 128))[sl];
        #pragma unroll
        for (int j = 0; j < 8; ++j) a[j] += (float)u0[j];
        #pragma unroll
        for (int j = 0; j < 8; ++j) a[j] += (float)u1[j];
    }
    for (; e + 4 <= e1; e += 4) {
        int s = csr[e + qtr];
        half8 u = ((const half8*)(Xp + (size_t)s * 128))[sl];
        #pragma unroll
        for (int j = 0; j < 8; ++j) a[j] += (float)u[j];
    }
    int rem = e1 - e;
    if (qtr < rem) {
        int s = csr[e + qtr];
        half8 u = ((const half8*)(Xp + (size_t)s * 128))[sl];
        #pragma unroll
        for (int j = 0; j < 8; ++j) a[j] += (float)u[j];
    }
    #pragma unroll
    for (int j = 0; j < 8; ++j) {
        a[j] += __shfl_xor(a[j], 16);
        a[j] += __shfl_xor(a[j], 32);
    }
    if (lane < 16) {
        float inv = 1.0f / fmaxf((float)(e1 - e0), 1.0f);
        half8 rh;
        #pragma unroll
        for (int j = 0; j < 8; ++j) rh[j] = (_Float16)(a[j] * inv);
        ((half8*)(Pp + (size_t)node * 128))[sl] = rh;
    }
}

// Layer-3 finish: out[node][0:47] = S[node] + mean(Y[nbrs]).
__global__ __launch_bounds__(256) void agg_l3(const _Float16* __restrict__ Y,
                                              const float* __restrict__ S,
                                              const int* __restrict__ csr,
                                              const int* __restrict__ offs,
                                              float* __restrict__ out, int n) {
    int node = blockIdx.x * 4 + (threadIdx.x >> 6);
    int lane = threadIdx.x & 63;
    int qtr = lane >> 4;
    int sl = lane & 15;
    int c = sl < 12 ? sl : 11;
    if (node >= n) return;
    int e0 = offs[node], e1 = offs[node + 1];
    float a0 = 0.f, a1 = 0.f, a2 = 0.f, a3 = 0.f;
    int e = e0;
    for (; e + 8 <= e1; e += 8) {
        int s0 = csr[e + qtr];
        int s1 = csr[e + 4 + qtr];
        half4v f0 = ((const half4v*)(Y + (size_t)s0 * 48))[c];
        half4v f1 = ((const half4v*)(Y + (size_t)s1 * 48))[c];
        a0 += (float)f0[0] + (float)f1[0];
        a1 += (float)f0[1] + (float)f1[1];
        a2 += (float)f0[2] + (float)f1[2];
        a3 += (float)f0[3] + (float)f1[3];
    }
    for (; e + 4 <= e1; e += 4) {
        int s = csr[e + qtr];
        half4v f = ((const half4v*)(Y + (size_t)s * 48))[c];
        a0 += (float)f[0]; a1 += (float)f[1]; a2 += (float)f[2]; a3 += (float)f[3];
    }
    int rem = e1 - e;
    if (qtr < rem) {
        int s = csr[e + qtr];
        half4v f = ((const half4v*)(Y + (size_t)s * 48))[c];
        a0 += (float)f[0]; a1 += (float)f[1]; a2 += (float)f[2]; a3 += (float)f[3];
    }
    a0 += __shfl_xor(a0, 16); a0 += __shfl_xor(a0, 32);
    a1 += __shfl_xor(a1, 16); a1 += __shfl_xor(a1, 32);
    a2 += __shfl_xor(a2, 16); a2 += __shfl_xor(a2, 32);
    a3 += __shfl_xor(a3, 16); a3 += __shfl_xor(a3, 32);
    if (lane < 12) {
        float inv = 1.0f / fmaxf((float)(e1 - e0), 1.0f);
        float4 sv = ((const float4*)(S + (size_t)node * 48))[c];
        float r[4] = {sv.x + a0 * inv, sv.y + a1 * inv, sv.z + a2 * inv, sv.w + a3 * inv};
        #pragma unroll
        for (int k = 0; k < 4; ++k) {
            int col = c * 4 + k;
            if (col < 47) out[(size_t)node * 47 + col] = r[k];
        }
    }
}

// ---------------- MFMA GEMM, 64-row x (NTILES*16)-col blocks ---------------
// TLP version: one m-tile per wave (acc[NTILES] = 32 AGPR at NTILES=8) so
// ~140 regs total -> 3-4 waves/SIMD (vs 2 at the old 128-row/acc[2][16]).
// Grid = (ceil(n/64), col-blocks). LDS ping-pong B staging (all 256 threads
// stage: 2 threads per B-row, 32 B each), one raw barrier per k-step, vmcnt
// never drained (r5 structure). A planes: element (r,k) at
// base + (k>>7)*n*128 + r*128 + (k&127).
// OUTFMT 1: fp16 plane write. OUTFMT 2 (colbase=0): cols 0-47 -> S fp32
// (+bias), cols 48-95 -> Y fp16 (stride 48).
// NOT safe for in-place A==out when gridDim.y>1 (sibling col-block reads the
// plane this block writes) -- L2 uses H2 double-buffer or the fallback below.

template <int NTILES, int OUTFMT>
__global__ __launch_bounds__(256, 3) void gemm64(
    const _Float16* __restrict__ A1h, const _Float16* __restrict__ A2h,
    const _Float16* __restrict__ W1, const _Float16* __restrict__ W2,
    const float* __restrict__ bias, float* __restrict__ outS, _Float16* __restrict__ outY,
    _Float16* __restrict__ outh, int n, int K, int relu, int phases) {
    constexpr int NPAD = NTILES * 16;
    constexpr int LDT = 36;
    __shared__ _Float16 Bs[2][NPAD * LDT];

    const int t = threadIdx.x;
    const int bm = blockIdx.x * 64;
    const int colbase = blockIdx.y * NPAD;
    const int lane = t & 63;
    const int w = t >> 6;
    const int quad = lane >> 4;
    const int tl = lane & 15;
    const int r0 = bm + w * 16 + tl;
    const size_t PS = (size_t)n * 128;   // plane stride

    floatx4 acc[NTILES];
    #pragma unroll
    for (int j = 0; j < NTILES; ++j) acc[j] = (floatx4){0.f, 0.f, 0.f, 0.f};

    const int spp = K >> 5;
    const int nsteps = phases * spp;     // always even (8 or 16)

    const int tr = t >> 1;               // staged B row
    const int koff = (t & 1) * 16;       // half-offset in the 32-half k-slice
    const bool stager = (t < 2 * NPAD);

    half8 pb0, pb1;                      // W regs for the NEXT stage
    half8 aA = {0}, aB = {0};            // A ring, depth 2

    auto wload = [&](int s2) {
        int ph2 = (s2 >= spp) ? 1 : 0;
        int k02 = (ph2 ? s2 - spp : s2) << 5;
        const _Float16* W = ph2 ? W2 : W1;
        const half8* p = (const half8*)(W + (size_t)(colbase + tr) * K + k02 + koff);
        pb0 = p[0]; pb1 = p[1];
    };
    auto aload = [&](int s2, half8& d) {
        int ph2 = (s2 >= spp) ? 1 : 0;
        int k02 = (ph2 ? s2 - spp : s2) << 5;
        const _Float16* Ah = ph2 ? A2h : A1h;
        int kq = k02 + quad * 8;
        const _Float16* Ab = Ah + ((kq >> 7) ? PS : (size_t)0) + (kq & 127);
        d = (half8){0};
        if (r0 < n) d = *(const half8*)(Ab + (size_t)r0 * 128);
    };

    // prologue: Bs[0] <- W(0); regs <- W(1); A ring <- A(0), A(1)
    if (stager) {
        wload(0);
        *(half8*)&Bs[0][tr * LDT + koff]     = pb0;
        *(half8*)&Bs[0][tr * LDT + koff + 8] = pb1;
        wload(1);
    }
    aload(0, aA);
    aload(1, aB);
    __syncthreads();

    for (int s = 0; s < nsteps; s += 2) {
        // ---- even stage s: read Bs[0]; write Bs[1] = W(s+1); A slot A
        {
            if (s + 1 < nsteps && stager) {
                *(half8*)&Bs[1][tr * LDT + koff]     = pb0;
                *(half8*)&Bs[1][tr * LDT + koff + 8] = pb1;
                if (s + 2 < nsteps) wload(s + 2);
            }
            half8 ca = aA;
            if (s + 2 < nsteps) aload(s + 2, aA);
            #pragma unroll
            for (int nt = 0; nt < NTILES; ++nt) {
                half8 bh = *(const half8*)&Bs[0][(nt * 16 + tl) * LDT + quad * 8];
                acc[nt] = __builtin_amdgcn_mfma_f32_16x16x32_f16(ca, bh, acc[nt], 0, 0, 0);
            }
            asm volatile("s_waitcnt lgkmcnt(0)" ::: "memory");
            __builtin_amdgcn_sched_barrier(0);
            __builtin_amdgcn_s_barrier();
        }
        // ---- odd stage s+1: read Bs[1]; write Bs[0] = W(s+2); A slot B
        {
            int s1 = s + 1;
            if (s1 + 1 < nsteps && stager) {
                *(half8*)&Bs[0][tr * LDT + koff]     = pb0;
                *(half8*)&Bs[0][tr * LDT + koff + 8] = pb1;
                if (s1 + 2 < nsteps) wload(s1 + 2);
            }
            half8 ca = aB;
            if (s1 + 2 < nsteps) aload(s1 + 2, aB);
            #pragma unroll
            for (int nt = 0; nt < NTILES; ++nt) {
                half8 bh = *(const half8*)&Bs[1][(nt * 16 + tl) * LDT + quad * 8];
                acc[nt] = __builtin_amdgcn_mfma_f32_16x16x32_f16(ca, bh, acc[nt], 0, 0, 0);
            }
            asm volatile("s_waitcnt lgkmcnt(0)" ::: "memory");
            __builtin_amdgcn_sched_barrier(0);
            __builtin_amdgcn_s_barrier();
        }
    }

    #pragma unroll
    for (int nt = 0; nt < NTILES; ++nt) {
        int gc = colbase + nt * 16 + tl;
        #pragma unroll
        for (int r = 0; r < 4; ++r) {
            int gr = bm + w * 16 + quad * 4 + r;
            if (gr >= n) continue;
            float v = acc[nt][r];
            if (OUTFMT == 1) {
                v += bias[gc];
                if (relu) v = fmaxf(v, 0.f);
                outh[(size_t)(gc >> 7) * PS + (size_t)gr * 128 + (gc & 127)] = (_Float16)v;
            } else {
                if (gc < 48) {
                    v += (gc < 47) ? bias[gc] : 0.f;
                    outS[(size_t)gr * 48 + gc] = v;
                } else {
                    outY[(size_t)gr * 48 + (gc - 48)] = (_Float16)v;
                }
            }
        }
    }
}

// ---------------- fallback in-place GEMM (r5 structure, 128x256 blocks) -----
// Used for layer 2 only when the workspace can't hold the H2 double buffer.

template <int NTILES, int OUTFMT>
__global__ __launch_bounds__(256, 2) void gemm_mfma(
    const _Float16* __restrict__ A1h, const _Float16* __restrict__ A2h,
    const _Float16* __restrict__ W1, const _Float16* __restrict__ W2,
    const float* __restrict__ bias, float* __restrict__ outS, _Float16* __restrict__ outY,
    _Float16* __restrict__ outh, int n, int K, int dout, int relu, int phases) {
    constexpr int NPAD = NTILES * 16;
    constexpr int LDT = 36;
    __shared__ _Float16 Bs[2][NPAD * LDT];

    const int t = threadIdx.x;
    const int bm = blockIdx.x * 128;
    const int lane = t & 63;
    const int w = t >> 6;
    const int quad = lane >> 4;
    const int tl = lane & 15;
    const int r0 = bm + w * 32 + tl;
    const int r1 = r0 + 16;
    const size_t PS = (size_t)n * 128;

    floatx4 acc[2][NTILES];
    #pragma unroll
    for (int i = 0; i < 2; ++i)
        #pragma unroll
        for (int j = 0; j < NTILES; ++j) acc[i][j] = (floatx4){0.f, 0.f, 0.f, 0.f};

    const int spp = K >> 5;
    const int nsteps = phases * spp;

    half8 pb0, pb1, pb2, pb3;
    half8 a0A = {0}, a1A = {0}, a0B = {0}, a1B = {0};

    auto wload = [&](int s2) {
        int ph2 = (s2 >= spp) ? 1 : 0;
        int k02 = (ph2 ? s2 - spp : s2) << 5;
        const _Float16* W = ph2 ? W2 : W1;
        const half8* p = (const half8*)(W + (size_t)t * K + k02);
        pb0 = p[0]; pb1 = p[1]; pb2 = p[2]; pb3 = p[3];
    };
    auto aload = [&](int s2, half8& d0, half8& d1) {
        int ph2 = (s2 >= spp) ? 1 : 0;
        int k02 = (ph2 ? s2 - spp : s2) << 5;
        const _Float16* Ah = ph2 ? A2h : A1h;
        int kq = k02 + quad * 8;
        const _Float16* Ab = Ah + ((kq >> 7) ? PS : (size_t)0) + (kq & 127);
        d0 = (half8){0}; d1 = (half8){0};
        if (r0 < n) d0 = *(const half8*)(Ab + (size_t)r0 * 128);
        if (r1 < n) d1 = *(const half8*)(Ab + (size_t)r1 * 128);
    };

    if (t < NPAD) {
        wload(0);
        *(half8*)&Bs[0][t * LDT + 0]  = pb0;
        *(half8*)&Bs[0][t * LDT + 8]  = pb1;
        *(half8*)&Bs[0][t * LDT + 16] = pb2;
        *(half8*)&Bs[0][t * LDT + 24] = pb3;
        wload(1);
    }
    aload(0, a0A, a1A);
    aload(1, a0B, a1B);
    __syncthreads();

    for (int s = 0; s < nsteps; s += 2) {
        {
            if (s + 1 < nsteps && t < NPAD) {
                *(half8*)&Bs[1][t * LDT + 0]  = pb0;
                *(half8*)&Bs[1][t * LDT + 8]  = pb1;
                *(half8*)&Bs[1][t * LDT + 16] = pb2;
                *(half8*)&Bs[1][t * LDT + 24] = pb3;
                if (s + 2 < nsteps) wload(s + 2);
            }
            half8 ca0 = a0A, ca1 = a1A;
            if (s + 2 < nsteps) aload(s + 2, a0A, a1A);
            #pragma unroll
            for (int nt = 0; nt < NTILES; ++nt) {
                half8 bh = *(const half8*)&Bs[0][(nt * 16 + tl) * LDT + quad * 8];
                acc[0][nt] = __builtin_amdgcn_mfma_f32_16x16x32_f16(ca0, bh, acc[0][nt], 0, 0, 0);
                acc[1][nt] = __builtin_amdgcn_mfma_f32_16x16x32_f16(ca1, bh, acc[1][nt], 0, 0, 0);
            }
            asm volatile("s_waitcnt lgkmcnt(0)" ::: "memory");
            __builtin_amdgcn_sched_barrier(0);
            __builtin_amdgcn_s_barrier();
        }
        {
            int s1 = s + 1;
            if (s1 + 1 < nsteps && t < NPAD) {
                *(half8*)&Bs[0][t * LDT + 0]  = pb0;
                *(half8*)&Bs[0][t * LDT + 8]  = pb1;
                *(half8*)&Bs[0][t * LDT + 16] = pb2;
                *(half8*)&Bs[0][t * LDT + 24] = pb3;
                if (s1 + 2 < nsteps) wload(s1 + 2);
            }
            half8 ca0 = a0B, ca1 = a1B;
            if (s1 + 2 < nsteps) aload(s1 + 2, a0B, a1B);
            #pragma unroll
            for (int nt = 0; nt < NTILES; ++nt) {
                half8 bh = *(const half8*)&Bs[1][(nt * 16 + tl) * LDT + quad * 8];
                acc[0][nt] = __builtin_amdgcn_mfma_f32_16x16x32_f16(ca0, bh, acc[0][nt], 0, 0, 0);
                acc[1][nt] = __builtin_amdgcn_mfma_f32_16x16x32_f16(ca1, bh, acc[1][nt], 0, 0, 0);
            }
            asm volatile("s_waitcnt lgkmcnt(0)" ::: "memory");
            __builtin_amdgcn_sched_barrier(0);
            __builtin_amdgcn_s_barrier();
        }
    }

    #pragma unroll
    for (int mt = 0; mt < 2; ++mt) {
        #pragma unroll
        for (int nt = 0; nt < NTILES; ++nt) {
            int gc = nt * 16 + tl;
            if (OUTFMT == 1 && gc >= dout) continue;
            #pragma unroll
            for (int r = 0; r < 4; ++r) {
                int gr = bm + w * 32 + mt * 16 + quad * 4 + r;
                if (gr >= n) continue;
                float v = acc[mt][nt][r];
                if (OUTFMT == 1) {
                    v += bias[gc];
                    if (relu) v = fmaxf(v, 0.f);
                    outh[(size_t)(gc >> 7) * PS + (size_t)gr * 128 + (gc & 127)] = (_Float16)v;
                } else {
                    if (gc < 48) {
                        v += (gc < 47) ? bias[gc] : 0.f;
                        outS[(size_t)gr * 48 + gc] = v;
                    } else {
                        outY[(size_t)gr * 48 + (gc - 48)] = (_Float16)v;
                    }
                }
            }
        }
    }
}

extern "C" void kernel_launch(void* const* d_in, const int* in_sizes, int n_in,
                              void* d_out, int out_size, void* d_ws, size_t ws_size,
                              hipStream_t stream) {
    (void)in_sizes; (void)n_in; (void)out_size;
    const int N = N_NODES, E = N_EDGES;
    const float* x = (const float*)d_in[0];
    const int* src = (const int*)d_in[1];
    const int* dst = (const int*)d_in[2];
    const float* w_self1 = (const float*)d_in[3];
    const float* w_neigh1 = (const float*)d_in[4];
    const float* b1 = (const float*)d_in[5];
    const float* w_self2 = (const float*)d_in[6];
    const float* w_neigh2 = (const float*)d_in[7];
    const float* b2 = (const float*)d_in[8];
    const float* w_self3 = (const float*)d_in[9];
    const float* w_neigh3 = (const float*)d_in[10];
    const float* b3 = (const float*)d_in[11];
    float* out = (float*)d_out;

    // workspace layout (~110 MB base + optional 51.2 MB H2)
    _Float16* Ph = (_Float16*)d_ws;             // N*256 fp16 (P planes P0|P1)
    _Float16* Hh = Ph + (size_t)N * 256;        // N*256 fp16 (H planes H0|H1)
    int* deg = (int*)(Hh + (size_t)N * 256);    // N
    int* offs = deg + N;                        // N+4
    int* csr = offs + N + 4;                    // E
    _Float16* wbuf = (_Float16*)(csr + E);
    _Float16* w1s = wbuf;                       // 256*128
    _Float16* w1n = w1s + 32768;                // 256*128
    _Float16* w2s = w1n + 32768;                // 256*256
    _Float16* w2n = w2s + 65536;                // 256*256
    _Float16* w3c = w2n + 65536;                // 96*256 combined [self|neigh]
    int* bsum = (int*)(w3c + 24576);            // 64
    int* bbase = bsum + 64;                     // NB+1
    // overlays on the Ph region:
    int* rank = (int*)Ph;                       // E ints, dead before aggP writes P0
    _Float16* xh = Ph + (size_t)N * 128;        // N*128 fp16 (layer 1)
    float* S = (float*)Ph;                      // N*48 fp32 (layer 3; P dead)
    _Float16* Y = (_Float16*)(S + (size_t)N * 48);  // N*48 fp16
    // optional H2 double buffer (for the col-split L2 gemm)
    size_t used = (size_t)((char*)(bbase + 64) - (char*)d_ws);
    used = (used + 255) & ~(size_t)255;
    _Float16* H2 = (_Float16*)((char*)d_ws + used);
    const bool dbuf = (used + (size_t)N * 256 * sizeof(_Float16)) <= ws_size;

    const int NB = (N + 2047) / 2048;           // 49 scan blocks

    hipMemsetAsync(deg, 0, N * sizeof(int), stream);
    deg_rank<<<(E + 255) / 256, 256, 0, stream>>>(dst, deg, rank, E);
    scan_partial<<<NB, 256, 0, stream>>>(deg, bsum, N);
    scan_blocksums<<<1, 64, 0, stream>>>(bsum, bbase, NB);
    scan_write<<<NB, 256, 0, stream>>>(deg, bbase, offs, N, NB);
    fill_csr2<<<(E + 255) / 256, 256, 0, stream>>>(src, dst, offs, rank, csr, E);

    cvt_f16<<<(N * 128 / 4 + 255) / 256, 256, 0, stream>>>((const float4*)x, (half4v*)xh,
                                                           N * 128 / 4);
    prep_all<<<(221184 + 255) / 256, 256, 0, stream>>>(w_self1, w_neigh1, w_self2, w_neigh2,
                                                       w_self3, w_neigh3, w1s, w1n, w2s, w2n,
                                                       w3c);

    const int g64 = (N + 63) / 64;              // 1563
    int aggGrid = (N + 3) / 4;

    // layer 1: 128 -> 256, relu (not in-place: reads xh/Ph, writes Hh planes)
    aggP<<<aggGrid, 256, 0, stream>>>(xh, csr, offs, Ph, N);
    gemm64<8, 1><<<dim3(g64, 2), 256, 0, stream>>>(xh, Ph, w1s, w1n, b1, nullptr, nullptr,
                                                   Hh, N, 128, 1, 2);
    // layer 2: 256 -> 256, relu. Aggregate each H plane; col-split gemm writes
    // H2 (double buffer) -- in-place is racy across sibling col-blocks.
    aggP<<<aggGrid, 256, 0, stream>>>(Hh, csr, offs, Ph, N);
    aggP<<<aggGrid, 256, 0, stream>>>(Hh + (size_t)N * 128, csr, offs, Ph + (size_t)N * 128, N);
    const _Float16* Hcur;
    if (dbuf) {
        gemm64<8, 1><<<dim3(g64, 2), 256, 0, stream>>>(Hh, Ph, w2s, w2n, b2, nullptr, nullptr,
                                                       H2, N, 256, 1, 2);
        Hcur = H2;
    } else {
        gemm_mfma<16, 1><<<(N + 127) / 128, 256, 0, stream>>>(Hh, Ph, w2s, w2n, b2, nullptr,
                                                              nullptr, Hh, N, 256, 256, 1, 2);
        Hcur = Hh;
    }
    // layer 3: S = H@Ws3+b3 (fp32), Y = H@Wn3 (fp16), then out = S + mean(Y).
    gemm64<6, 2><<<dim3(g64, 1), 256, 0, stream>>>(Hcur, nullptr, w3c, nullptr, b3, S, Y,
                                                   nullptr, N, 256, 0, 1);
    agg_l3<<<aggGrid, 256, 0, stream>>>(Y, S, csr, offs, out, N);
}